// Round 17
// baseline (549.548 us; speedup 1.0000x reference)
//
#include <hip/hip_runtime.h>

// HashEmbedding (Instant-NGP hash grid), MI355X gfx950.
// Round 17: R13 base (counting sort + sorted flat gather + XCD chunk) +
// XOR-adjacency float4 pairing with per-level sched_barrier(0) fences.
// Corners (c,c+4) differ by v0 -> v0+1 = idx^1 when v0 even -> one aligned
// 16B float4 covers both. Odd-v0 lanes take 4 exec-masked fixup loads.
// TA lane-slots/level: 8 -> ~6. The sched_barrier stops the cross-level
// load clustering that spilled 2.5KB/thread in R14/R15.

#define NLVL 16
#define TMASK ((1u << 19) - 1u)
#define P1 2654435761u
#define P2 805459861u
#define NBINS 32768         // 32 x 32 x 32

__constant__ float c_res[NLVL] = {16.f, 20.f, 25.f, 32.f, 40.f, 50.f, 64.f, 80.f,
                                  101.f, 128.f, 161.f, 203.f, 256.f, 322.f, 406.f, 512.f};

__device__ __forceinline__ int bin_of(float xn0, float xn1, float xn2)
{
    int bx = (int)((xn0 - 0.5f) * 64.f);
    int by = (int)((xn1 - 0.5f) * 64.f);
    int bz = (int)((xn2 - 0.5f) * 64.f);
    bx = bx < 0 ? 0 : (bx > 31 ? 31 : bx);
    by = by < 0 ? 0 : (by > 31 ? 31 : by);
    bz = bz < 0 ? 0 : (bz > 31 ? 31 : bz);
    return (bx << 10) | (by << 5) | bz;
}

__device__ __forceinline__ float2 sel_half(const float4 v, unsigned odd)
{
    return odd ? make_float2(v.z, v.w) : make_float2(v.x, v.y);
}

// ---- Pass 1: count points per bin ----
__global__ __launch_bounds__(256)
void k_count(const float* __restrict__ x, unsigned* __restrict__ counts)
{
    const int p = blockIdx.x * 256 + threadIdx.x;
    const float xn0 = (x[3 * p + 0] + 1.0f) * 0.5f;
    const float xn1 = (x[3 * p + 1] + 1.0f) * 0.5f;
    const float xn2 = (x[3 * p + 2] + 1.0f) * 0.5f;
    atomicAdd(&counts[bin_of(xn0, xn1, xn2)], 1u);
}

// ---- Pass 2: exclusive scan of counts -> cursor ----
__global__ __launch_bounds__(1024)
void k_scan(const unsigned* __restrict__ counts, unsigned* __restrict__ cursor)
{
    __shared__ unsigned s[1024];
    const int t = threadIdx.x;
    unsigned loc[32];
    unsigned sum = 0;
#pragma unroll
    for (int i = 0; i < 32; ++i) {
        loc[i] = sum;
        sum += counts[t * 32 + i];
    }
    s[t] = sum;
    __syncthreads();
    for (int off = 1; off < 1024; off <<= 1) {
        const unsigned v = (t >= off) ? s[t - off] : 0u;
        __syncthreads();
        s[t] += v;
        __syncthreads();
    }
    const unsigned blockbase = (t > 0) ? s[t - 1] : 0u;
#pragma unroll
    for (int i = 0; i < 32; ++i)
        cursor[t * 32 + i] = blockbase + loc[i];
}

// ---- Pass 3: place points in bin-sorted order ----
__global__ __launch_bounds__(256)
void k_place(const float* __restrict__ x,
             unsigned* __restrict__ cursor,
             float4* __restrict__ sorted_pts)
{
    const int p = blockIdx.x * 256 + threadIdx.x;
    const float xn0 = (x[3 * p + 0] + 1.0f) * 0.5f;
    const float xn1 = (x[3 * p + 1] + 1.0f) * 0.5f;
    const float xn2 = (x[3 * p + 2] + 1.0f) * 0.5f;
    const unsigned pos = atomicAdd(&cursor[bin_of(xn0, xn1, xn2)], 1u);
    float4 e;
    e.x = xn0; e.y = xn1; e.z = xn2; e.w = __uint_as_float((unsigned)p);
    sorted_pts[pos] = e;
}

// ---- Pass 4: sorted gather, XOR-paired loads, per-level sched fences ----
__global__ __launch_bounds__(256)
void k_gather_sorted(const float4* __restrict__ sorted_pts,
                     const float* __restrict__ tables,
                     float* __restrict__ out)
{
    const unsigned bid = blockIdx.x;
    const unsigned newbid = (bid & 7u) * 512u + (bid >> 3);
    const int sp = (int)(newbid * 256u + threadIdx.x);

    const float4 e = sorted_pts[sp];
    const float xn0 = e.x, xn1 = e.y, xn2 = e.z;
    const unsigned pidx = __float_as_uint(e.w);

    float o[2 * NLVL];
#pragma unroll
    for (int l = 0; l < NLVL; ++l) {
        const float2* __restrict__ tab = (const float2*)tables + ((size_t)l << 19);
        const float r = c_res[l];

        const float s0 = xn0 * r, s1 = xn1 * r, s2 = xn2 * r;
        const float f0 = floorf(s0), f1 = floorf(s1), f2 = floorf(s2);
        const float w0 = s0 - f0, w1 = s1 - f1, w2 = s2 - f2;
        const unsigned v0 = (unsigned)(int)f0;
        const unsigned v1 = (unsigned)(int)f1;
        const unsigned v2 = (unsigned)(int)f2;

        const unsigned bx0 = v1 * P1;
        const unsigned bx1 = (v1 + 1u) * P1;
        const unsigned cx0 = v2 * P2;
        const unsigned cx1 = (v2 + 1u) * P2;

        const unsigned i0 = (v0 ^ bx0 ^ cx0) & TMASK;
        const unsigned i1 = (v0 ^ bx0 ^ cx1) & TMASK;
        const unsigned i2 = (v0 ^ bx1 ^ cx0) & TMASK;
        const unsigned i3 = (v0 ^ bx1 ^ cx1) & TMASK;
        const unsigned j0 = ((v0 + 1u) ^ bx0 ^ cx0) & TMASK;
        const unsigned j1 = ((v0 + 1u) ^ bx0 ^ cx1) & TMASK;
        const unsigned j2 = ((v0 + 1u) ^ bx1 ^ cx0) & TMASK;
        const unsigned j3 = ((v0 + 1u) ^ bx1 ^ cx1) & TMASK;

        // paired 16B loads: cover (i_c, j_c) when v0 even (j_c == i_c^1)
        const float4 fA = *reinterpret_cast<const float4*>(tab + (i0 & ~1u));
        const float4 fB = *reinterpret_cast<const float4*>(tab + (i1 & ~1u));
        const float4 fC = *reinterpret_cast<const float4*>(tab + (i2 & ~1u));
        const float4 fD = *reinterpret_cast<const float4*>(tab + (i3 & ~1u));

        const float2 e0 = sel_half(fA, i0 & 1u);
        const float2 e1 = sel_half(fB, i1 & 1u);
        const float2 e2 = sel_half(fC, i2 & 1u);
        const float2 e3 = sel_half(fD, i3 & 1u);
        float2 e4 = sel_half(fA, j0 & 1u);
        float2 e5 = sel_half(fB, j1 & 1u);
        float2 e6 = sel_half(fC, j2 & 1u);
        float2 e7 = sel_half(fD, j3 & 1u);

        // exec-masked fixups for odd-v0 lanes (~50% active)
        if (v0 & 1u) {
            e4 = tab[j0];
            e5 = tab[j1];
            e6 = tab[j2];
            e7 = tab[j3];
        }

        const float omx = 1.0f - w0, omy = 1.0f - w1, omz = 1.0f - w2;
        const float c00x = e0.x * omx + e4.x * w0;
        const float c00y = e0.y * omx + e4.y * w0;
        const float c01x = e1.x * omx + e5.x * w0;
        const float c01y = e1.y * omx + e5.y * w0;
        const float c10x = e2.x * omx + e6.x * w0;
        const float c10y = e2.y * omx + e6.y * w0;
        const float c11x = e3.x * omx + e7.x * w0;
        const float c11y = e3.y * omx + e7.y * w0;
        const float c0x = c00x * omy + c10x * w1;
        const float c0y = c00y * omy + c10y * w1;
        const float c1x = c01x * omy + c11x * w1;
        const float c1y = c01y * omy + c11y * w1;
        o[2 * l + 0] = c0x * omz + c1x * w2;
        o[2 * l + 1] = c0y * omz + c1y * w2;

        // forbid cross-level instruction motion: bounds the load live-range
        // to one level (R14/R15 spilled 2.5KB/thread without this).
        __builtin_amdgcn_sched_barrier(0);
    }

    float4* op = (float4*)(out + (size_t)pidx * 32);
#pragma unroll
    for (int q = 0; q < 8; ++q)
        op[q] = make_float4(o[4 * q], o[4 * q + 1], o[4 * q + 2], o[4 * q + 3]);
}

// ---- Fallback: single-kernel f32 version (unexpected n or small ws) ----
__global__ __launch_bounds__(256)
void hash_embed_fallback(const float* __restrict__ x,
                         const float* __restrict__ tables,
                         float* __restrict__ out,
                         int n)
{
    const int p = blockIdx.x * 256 + threadIdx.x;
    if (p >= n) return;

    const float xn0 = (x[3 * p + 0] + 1.0f) * 0.5f;
    const float xn1 = (x[3 * p + 1] + 1.0f) * 0.5f;
    const float xn2 = (x[3 * p + 2] + 1.0f) * 0.5f;

    float o[2 * NLVL];
#pragma unroll
    for (int l = 0; l < NLVL; ++l) {
        const float2* tab = (const float2*)tables + ((size_t)l << 19);
        const float r = c_res[l];
        const float s0 = xn0 * r, s1 = xn1 * r, s2 = xn2 * r;
        const float f0 = floorf(s0), f1 = floorf(s1), f2 = floorf(s2);
        const float w0 = s0 - f0, w1 = s1 - f1, w2 = s2 - f2;
        const unsigned v0 = (unsigned)(int)f0;
        const unsigned v1 = (unsigned)(int)f1;
        const unsigned v2 = (unsigned)(int)f2;
        const unsigned bx0 = v1 * P1, bx1 = (v1 + 1u) * P1;
        const unsigned cx0 = v2 * P2, cx1 = (v2 + 1u) * P2;
        const float2 e0 = tab[(v0 ^ bx0 ^ cx0) & TMASK];
        const float2 e1 = tab[(v0 ^ bx0 ^ cx1) & TMASK];
        const float2 e2 = tab[(v0 ^ bx1 ^ cx0) & TMASK];
        const float2 e3 = tab[(v0 ^ bx1 ^ cx1) & TMASK];
        const float2 e4 = tab[((v0 + 1u) ^ bx0 ^ cx0) & TMASK];
        const float2 e5 = tab[((v0 + 1u) ^ bx0 ^ cx1) & TMASK];
        const float2 e6 = tab[((v0 + 1u) ^ bx1 ^ cx0) & TMASK];
        const float2 e7 = tab[((v0 + 1u) ^ bx1 ^ cx1) & TMASK];
        const float omx = 1.f - w0, omy = 1.f - w1, omz = 1.f - w2;
        const float c00x = e0.x * omx + e4.x * w0;
        const float c00y = e0.y * omx + e4.y * w0;
        const float c01x = e1.x * omx + e5.x * w0;
        const float c01y = e1.y * omx + e5.y * w0;
        const float c10x = e2.x * omx + e6.x * w0;
        const float c10y = e2.y * omx + e6.y * w0;
        const float c11x = e3.x * omx + e7.x * w0;
        const float c11y = e3.y * omx + e7.y * w0;
        const float c0x = c00x * omy + c10x * w1;
        const float c0y = c00y * omy + c10y * w1;
        const float c1x = c01x * omy + c11x * w1;
        const float c1y = c01y * omy + c11y * w1;
        o[2 * l + 0] = c0x * omz + c1x * w2;
        o[2 * l + 1] = c0y * omz + c1y * w2;
    }

    float4* op = (float4*)(out + (size_t)p * 32);
#pragma unroll
    for (int q = 0; q < 8; ++q)
        op[q] = make_float4(o[4 * q], o[4 * q + 1], o[4 * q + 2], o[4 * q + 3]);
}

extern "C" void kernel_launch(void* const* d_in, const int* in_sizes, int n_in,
                              void* d_out, int out_size, void* d_ws, size_t ws_size,
                              hipStream_t stream) {
    const float* x = (const float*)d_in[0];
    const float* tables = (const float*)d_in[1];
    float* out = (float*)d_out;
    const int n = in_sizes[0] / 3;                       // 1048576

    char* ws = (char*)d_ws;
    float4*   sorted_pts = (float4*)ws;                                        // 16 MB
    unsigned* counts     = (unsigned*)(ws + ((size_t)16 << 20));               // 128 KB
    unsigned* cursor     = (unsigned*)(ws + ((size_t)16 << 20) + (128 << 10)); // 128 KB
    const size_t ws_needed = ((size_t)16 << 20) + (256 << 10);

    if (n == (1 << 20) && ws_size >= ws_needed) {
        hipMemsetAsync(counts, 0, NBINS * sizeof(unsigned), stream);
        k_count<<<4096, 256, 0, stream>>>(x, counts);
        k_scan<<<1, 1024, 0, stream>>>(counts, cursor);
        k_place<<<4096, 256, 0, stream>>>(x, cursor, sorted_pts);
        k_gather_sorted<<<4096, 256, 0, stream>>>(sorted_pts, tables, out);
    } else {
        hash_embed_fallback<<<(n + 255) / 256, 256, 0, stream>>>(x, tables, out, n);
    }
}

// Round 18
// 324.339 us; speedup vs baseline: 1.6944x; 1.6944x over previous
//
#include <hip/hip_runtime.h>

// HashEmbedding (Instant-NGP hash grid), MI355X gfx950.
// Round 18 = Round 13 restored (best verified: 324.6 us).
// Structure: 3-pass spatial counting sort (32^3 bins over occupied half-cube)
// + flat sorted gather with XCD chunking and (compiler-rolled) level loop.
// The gather runs at 0.96 divergent lane-addresses/cycle/CU = 104% of the
// TA address-issue structural floor (218 us for 134M divergent gathers).
// Falsified levers: L2 partitioning (R3/R5), L1 bypass (R9), XCD swizzle
// variants (R12), MLP widening (R6), LDS corner staging (R10/R16: occupancy
// collapse), XOR load pairing (R7 null; R14/R15/R17 compiler spill/regalloc).

#define NLVL 16
#define TMASK ((1u << 19) - 1u)
#define P1 2654435761u
#define P2 805459861u
#define NBINS 32768         // 32 x 32 x 32

__constant__ float c_res[NLVL] = {16.f, 20.f, 25.f, 32.f, 40.f, 50.f, 64.f, 80.f,
                                  101.f, 128.f, 161.f, 203.f, 256.f, 322.f, 406.f, 512.f};

__device__ __forceinline__ int bin_of(float xn0, float xn1, float xn2)
{
    int bx = (int)((xn0 - 0.5f) * 64.f);
    int by = (int)((xn1 - 0.5f) * 64.f);
    int bz = (int)((xn2 - 0.5f) * 64.f);
    bx = bx < 0 ? 0 : (bx > 31 ? 31 : bx);
    by = by < 0 ? 0 : (by > 31 ? 31 : by);
    bz = bz < 0 ? 0 : (bz > 31 ? 31 : bz);
    return (bx << 10) | (by << 5) | bz;
}

__device__ __forceinline__ void corner_idx(float xn0, float xn1, float xn2, float r,
                                           unsigned idx[8], float& w0, float& w1, float& w2)
{
    const float s0 = xn0 * r;
    const float s1 = xn1 * r;
    const float s2 = xn2 * r;
    const float f0 = floorf(s0);
    const float f1 = floorf(s1);
    const float f2 = floorf(s2);
    w0 = s0 - f0;
    w1 = s1 - f1;
    w2 = s2 - f2;
    const unsigned v0 = (unsigned)(int)f0;
    const unsigned v1 = (unsigned)(int)f1;
    const unsigned v2 = (unsigned)(int)f2;

    const unsigned ax0 = v0;
    const unsigned ax1 = v0 + 1u;
    const unsigned bx0 = v1 * P1;
    const unsigned bx1 = (v1 + 1u) * P1;
    const unsigned cx0 = v2 * P2;
    const unsigned cx1 = (v2 + 1u) * P2;

    idx[0] = (ax0 ^ bx0 ^ cx0) & TMASK;
    idx[1] = (ax0 ^ bx0 ^ cx1) & TMASK;
    idx[2] = (ax0 ^ bx1 ^ cx0) & TMASK;
    idx[3] = (ax0 ^ bx1 ^ cx1) & TMASK;
    idx[4] = (ax1 ^ bx0 ^ cx0) & TMASK;
    idx[5] = (ax1 ^ bx0 ^ cx1) & TMASK;
    idx[6] = (ax1 ^ bx1 ^ cx0) & TMASK;
    idx[7] = (ax1 ^ bx1 ^ cx1) & TMASK;
}

__device__ __forceinline__ float2 trilerp(const float2 e[8], float w0, float w1, float w2)
{
    const float omx = 1.0f - w0;
    const float omy = 1.0f - w1;
    const float omz = 1.0f - w2;

    const float c00x = e[0].x * omx + e[4].x * w0;
    const float c00y = e[0].y * omx + e[4].y * w0;
    const float c01x = e[1].x * omx + e[5].x * w0;
    const float c01y = e[1].y * omx + e[5].y * w0;
    const float c10x = e[2].x * omx + e[6].x * w0;
    const float c10y = e[2].y * omx + e[6].y * w0;
    const float c11x = e[3].x * omx + e[7].x * w0;
    const float c11y = e[3].y * omx + e[7].y * w0;

    const float c0x = c00x * omy + c10x * w1;
    const float c0y = c00y * omy + c10y * w1;
    const float c1x = c01x * omy + c11x * w1;
    const float c1y = c01y * omy + c11y * w1;

    float2 o;
    o.x = c0x * omz + c1x * w2;
    o.y = c0y * omz + c1y * w2;
    return o;
}

// ---- Pass 1: count points per bin ----
__global__ __launch_bounds__(256)
void k_count(const float* __restrict__ x, unsigned* __restrict__ counts)
{
    const int p = blockIdx.x * 256 + threadIdx.x;
    const float xn0 = (x[3 * p + 0] + 1.0f) * 0.5f;
    const float xn1 = (x[3 * p + 1] + 1.0f) * 0.5f;
    const float xn2 = (x[3 * p + 2] + 1.0f) * 0.5f;
    atomicAdd(&counts[bin_of(xn0, xn1, xn2)], 1u);
}

// ---- Pass 2: exclusive scan of counts -> cursor (mutable bases) ----
__global__ __launch_bounds__(1024)
void k_scan(const unsigned* __restrict__ counts, unsigned* __restrict__ cursor)
{
    __shared__ unsigned s[1024];
    const int t = threadIdx.x;
    unsigned loc[32];
    unsigned sum = 0;
#pragma unroll
    for (int i = 0; i < 32; ++i) {
        loc[i] = sum;
        sum += counts[t * 32 + i];
    }
    s[t] = sum;
    __syncthreads();
    for (int off = 1; off < 1024; off <<= 1) {
        const unsigned v = (t >= off) ? s[t - off] : 0u;
        __syncthreads();
        s[t] += v;
        __syncthreads();
    }
    const unsigned blockbase = (t > 0) ? s[t - 1] : 0u;
#pragma unroll
    for (int i = 0; i < 32; ++i)
        cursor[t * 32 + i] = blockbase + loc[i];
}

// ---- Pass 3: place points in bin-sorted order ----
__global__ __launch_bounds__(256)
void k_place(const float* __restrict__ x,
             unsigned* __restrict__ cursor,
             float4* __restrict__ sorted_pts)
{
    const int p = blockIdx.x * 256 + threadIdx.x;
    const float xn0 = (x[3 * p + 0] + 1.0f) * 0.5f;
    const float xn1 = (x[3 * p + 1] + 1.0f) * 0.5f;
    const float xn2 = (x[3 * p + 2] + 1.0f) * 0.5f;
    const unsigned pos = atomicAdd(&cursor[bin_of(xn0, xn1, xn2)], 1u);
    float4 e;
    e.x = xn0; e.y = xn1; e.z = xn2; e.w = __uint_as_float((unsigned)p);
    sorted_pts[pos] = e;
}

// ---- Pass 4: flat gather in sorted order (XCD-chunked), write out[pidx] ----
__global__ __launch_bounds__(256, 4)
void k_gather_sorted(const float4* __restrict__ sorted_pts,
                     const float* __restrict__ tables,
                     float* __restrict__ out)
{
    const unsigned bid = blockIdx.x;
    const unsigned newbid = (bid & 7u) * 512u + (bid >> 3);
    const int sp = (int)(newbid * 256u + threadIdx.x);

    const float4 e = sorted_pts[sp];
    const float xn0 = e.x, xn1 = e.y, xn2 = e.z;
    const unsigned pidx = __float_as_uint(e.w);

    float o[2 * NLVL];

    // double-buffered fragment registers + weights (compiler rolls this, but
    // the shape measured best: 227us, VGPR 32, occupancy 72%)
    float2 eb0[8], eb1[8];
    float w0a, w1a, w2a, w0b, w1b, w2b;
    unsigned idx[8];

    corner_idx(xn0, xn1, xn2, c_res[0], idx, w0a, w1a, w2a);
    {
        const float2* __restrict__ tab = (const float2*)tables;
#pragma unroll
        for (int c = 0; c < 8; ++c) eb0[c] = tab[idx[c]];
    }

#pragma unroll
    for (int l = 0; l < NLVL; ++l) {
        if (l + 1 < NLVL) {
            const float2* __restrict__ tab =
                (const float2*)tables + ((size_t)(l + 1) << 19);
            if ((l & 1) == 0) {
                corner_idx(xn0, xn1, xn2, c_res[l + 1], idx, w0b, w1b, w2b);
#pragma unroll
                for (int c = 0; c < 8; ++c) eb1[c] = tab[idx[c]];
            } else {
                corner_idx(xn0, xn1, xn2, c_res[l + 1], idx, w0a, w1a, w2a);
#pragma unroll
                for (int c = 0; c < 8; ++c) eb0[c] = tab[idx[c]];
            }
        }
        const float2 v = ((l & 1) == 0) ? trilerp(eb0, w0a, w1a, w2a)
                                        : trilerp(eb1, w0b, w1b, w2b);
        o[2 * l + 0] = v.x;
        o[2 * l + 1] = v.y;
    }

    float4* op = (float4*)(out + (size_t)pidx * 32);
#pragma unroll
    for (int q = 0; q < 8; ++q)
        op[q] = make_float4(o[4 * q], o[4 * q + 1], o[4 * q + 2], o[4 * q + 3]);
}

// ---- Fallback: single-kernel f32 version (unexpected n or small ws) ----
__global__ __launch_bounds__(256)
void hash_embed_fallback(const float* __restrict__ x,
                         const float* __restrict__ tables,
                         float* __restrict__ out,
                         int n)
{
    const int p = blockIdx.x * 256 + threadIdx.x;
    if (p >= n) return;

    const float xn0 = (x[3 * p + 0] + 1.0f) * 0.5f;
    const float xn1 = (x[3 * p + 1] + 1.0f) * 0.5f;
    const float xn2 = (x[3 * p + 2] + 1.0f) * 0.5f;

    float o[2 * NLVL];
#pragma unroll
    for (int l = 0; l < NLVL; ++l) {
        const float2* tab = (const float2*)tables + ((size_t)l << 19);
        unsigned idx[8];
        float w0, w1, w2;
        corner_idx(xn0, xn1, xn2, c_res[l], idx, w0, w1, w2);
        float2 ee[8];
#pragma unroll
        for (int c = 0; c < 8; ++c) ee[c] = tab[idx[c]];
        const float2 v = trilerp(ee, w0, w1, w2);
        o[2 * l + 0] = v.x;
        o[2 * l + 1] = v.y;
    }

    float4* op = (float4*)(out + (size_t)p * 32);
#pragma unroll
    for (int q = 0; q < 8; ++q)
        op[q] = make_float4(o[4 * q], o[4 * q + 1], o[4 * q + 2], o[4 * q + 3]);
}

extern "C" void kernel_launch(void* const* d_in, const int* in_sizes, int n_in,
                              void* d_out, int out_size, void* d_ws, size_t ws_size,
                              hipStream_t stream) {
    const float* x = (const float*)d_in[0];
    const float* tables = (const float*)d_in[1];
    float* out = (float*)d_out;
    const int n = in_sizes[0] / 3;                       // 1048576

    char* ws = (char*)d_ws;
    float4*   sorted_pts = (float4*)ws;                                        // 16 MB
    unsigned* counts     = (unsigned*)(ws + ((size_t)16 << 20));               // 128 KB
    unsigned* cursor     = (unsigned*)(ws + ((size_t)16 << 20) + (128 << 10)); // 128 KB
    const size_t ws_needed = ((size_t)16 << 20) + (256 << 10);

    if (n == (1 << 20) && ws_size >= ws_needed) {
        hipMemsetAsync(counts, 0, NBINS * sizeof(unsigned), stream);
        k_count<<<4096, 256, 0, stream>>>(x, counts);
        k_scan<<<1, 1024, 0, stream>>>(counts, cursor);
        k_place<<<4096, 256, 0, stream>>>(x, cursor, sorted_pts);
        k_gather_sorted<<<4096, 256, 0, stream>>>(sorted_pts, tables, out);
    } else {
        hash_embed_fallback<<<(n + 255) / 256, 256, 0, stream>>>(x, tables, out, n);
    }
}